// Round 1
// baseline (45954.932 us; speedup 1.0000x reference)
//
#include <hip/hip_runtime.h>

// ---------------------------------------------------------------------------
// 2-layer LSTM (B=16, L=2048, H=1024) as ONE persistent scan kernel.
//
// Key facts driving the design:
//  * Layer 2's (h0,c0) = layer 1's FINAL state -> layers strictly sequential,
//    4096 sequential recurrent steps total. Sync-bound, not compute-bound.
//  * Per step, each of 256 blocks computes a [16 batch x 16 gate-row] tile of
//    g = [x_t | h_prev] @ [W|U]^T  (K=2048 concat) with mfma_f32_16x16x32_f16.
//  * Weights (fp16, both layers, 128 KiB/block) live in LDS for all steps,
//    XOR-swizzled to make ds_read_b128 bank-conflict-free.
//  * c-state lives in wave-0 registers for all 4096 steps (carries across the
//    layer boundary exactly as the reference does).
//  * Grid sync: two-level (8 groups x 32) device-scope atomic tree barrier.
// ---------------------------------------------------------------------------

typedef _Float16 half8 __attribute__((ext_vector_type(8)));
typedef float    float4v __attribute__((ext_vector_type(4)));

#define NBLK 256
#define NTHR 512
#define BB   16
#define LL   2048
#define HH   1024
#define KK   2048      // concat K (x-part 1024 + h-part 1024)
#define NJ   4         // h columns per block
#define NR   16        // gate rows per block (4 gates * NJ)
#define NSTEP 4096     // 2 layers * L

// ws layout (bytes)
#define WS_XT16   0u              // [L][B][H] fp16 : 64 MiB
#define WS_H1SEQ  67108864u       // [L][B][H] fp16 : 64 MiB
#define WS_HCUR   134217728u      // [2][B][H] fp16 : 64 KiB
#define WS_FLAGS  134283264u      // barrier flags

struct ScanParams {
  const float* W[4];     // Wf,Wi,Wo,Wc  [2][H][H]
  const float* U[4];     // Uf,Ui,Uo,Uc  [2][H][H]
  const float* bias4[4]; // bf,bi,bo,bc  [2][H]
  const _Float16* xT;    // [L][B][H]
  _Float16* h1seq;       // [L][B][H]
  _Float16* hcur;        // [2][B][H]
  float* dout;           // [B][L][H]
  unsigned* flags;
};

// x [B][L][H] fp32 -> xT [L][B][H] fp16
__global__ void prep_convert(const float* __restrict__ x, _Float16* __restrict__ xT) {
  size_t id = (size_t)blockIdx.x * blockDim.x + threadIdx.x;   // 4,194,304 total
  int k8 = (int)(id & (HH / 8 - 1)) * 8;
  size_t bt = id >> 7;                 // b*L + t
  int b = (int)(bt >> 11);
  int t = (int)(bt & (LL - 1));
  const float* src = x + (bt << 10) + k8;
  float4v v0 = *(const float4v*)(src);
  float4v v1 = *(const float4v*)(src + 4);
  half8 o;
  o[0] = (_Float16)v0[0]; o[1] = (_Float16)v0[1]; o[2] = (_Float16)v0[2]; o[3] = (_Float16)v0[3];
  o[4] = (_Float16)v1[0]; o[5] = (_Float16)v1[1]; o[6] = (_Float16)v1[2]; o[7] = (_Float16)v1[3];
  *(half8*)(xT + (((size_t)t * BB + b) << 10) + k8) = o;
}

__global__ void prep_init(_Float16* hcur, unsigned* flags) {
  int i = blockIdx.x * blockDim.x + threadIdx.x;
  if (i < 2 * BB * HH) hcur[i] = (_Float16)0.f;
  if (i < 1024) flags[i] = 0u;
}

__global__ __launch_bounds__(NTHR, 2) void lstm_scan(ScanParams p) {
  __shared__ _Float16 wlds[2][NR][KK];   // 131072 B, persistent weights
  __shared__ float acc_s[8][16][17];     // per-wave partial D tiles (padded)
  __shared__ float g_s[16][17];          // reduced gates
  __shared__ float bias_s[2][NR];

  const int tid  = threadIdx.x;
  const int blk  = blockIdx.x;
  const int wv   = tid >> 6;
  const int lane = tid & 63;
  const int frow = lane & 15;   // A: batch row ; B: gate row ; same lane mapping
  const int kgrp = lane >> 4;

  // ---- one-time: weights fp32 -> fp16 into LDS, XOR-swizzled rows ----
  for (int idx = tid; idx < 2 * NR * KK; idx += NTHR) {
    int l = idx >> 15;
    int r = (idx >> 11) & (NR - 1);      // r = q*4 + jj
    int k = idx & (KK - 1);
    int q = r >> 2, jj = r & 3;
    int j = blk * NJ + jj;
    float v;
    if (k < HH) v = p.W[q][((size_t)l * HH + j) * HH + k];
    else        v = p.U[q][((size_t)l * HH + j) * HH + (k - HH)];
    unsigned bo = ((unsigned)(k * 2)) ^ ((unsigned)((r & 7) << 4));
    *(_Float16*)((char*)&wlds[l][r][0] + bo) = (_Float16)v;
  }
  if (tid < 2 * NR) {
    int l = tid >> 4, r = tid & 15;
    int q = r >> 2, jj = r & 3;
    bias_s[l][r] = p.bias4[q][l * HH + blk * NJ + jj];
  }
  float c_state = 0.f;   // wave-0 lanes: cell (b = lane>>2, jj = lane&3)
  __syncthreads();

  unsigned* cnt1 = p.flags + (blk & 7) * 64;   // 8 level-1 counters, 256B apart
  unsigned* cntm = p.flags + 8 * 64;
  unsigned* gen  = p.flags + 9 * 64;

  for (int s = 0; s < NSTEP; ++s) {
    const int l    = s >> 11;
    const int t    = s & (LL - 1);
    const int rbuf = s & 1;

    // ---- phase A: per-wave K-slice MFMA ----
    const int kloc = (wv & 3) * 256;
    const _Float16* seg;
    if (wv < 4) {
      const _Float16* inp = (l == 0) ? p.xT : p.h1seq;
      seg = inp + (size_t)t * (BB * HH);
    } else {
      seg = p.hcur + (size_t)rbuf * (BB * HH);
    }
    const _Float16* abase = seg + frow * HH + kloc + kgrp * 8;
    const int kw0 = wv * 256 + kgrp * 8;

    half8 aop[8], bop[8];
#pragma unroll
    for (int kk = 0; kk < 8; ++kk)
      aop[kk] = *(const half8*)(abase + kk * 32);
    const char* wrow = (const char*)&wlds[l][frow][0];
#pragma unroll
    for (int kk = 0; kk < 8; ++kk) {
      unsigned bo = (unsigned)((kw0 + kk * 32) * 2) ^ ((unsigned)((frow & 7) << 4));
      bop[kk] = *(const half8*)(wrow + bo);
    }
    float4v a0 = {0.f, 0.f, 0.f, 0.f}, a1 = {0.f, 0.f, 0.f, 0.f};
#pragma unroll
    for (int kk = 0; kk < 8; kk += 2) {
      a0 = __builtin_amdgcn_mfma_f32_16x16x32_f16(aop[kk],     bop[kk],     a0, 0, 0, 0);
      a1 = __builtin_amdgcn_mfma_f32_16x16x32_f16(aop[kk + 1], bop[kk + 1], a1, 0, 0, 0);
    }
    a0 += a1;
#pragma unroll
    for (int v = 0; v < 4; ++v)
      acc_s[wv][kgrp * 4 + v][frow] = a0[v];   // D: row=batch=(lane>>4)*4+v, col=gaterow=lane&15
    __syncthreads();

    // ---- phase B: reduce 8 partials + bias ----
    if (tid < 256) {
      int b = tid >> 4, r = tid & 15;
      float g = bias_s[l][r];
#pragma unroll
      for (int w = 0; w < 8; ++w) g += acc_s[w][b][r];
      g_s[b][r] = g;
    }
    __syncthreads();

    // ---- phase C: LSTM cell update (wave 0, one lane per (b,jj)) ----
    if (tid < 64) {
      int b = tid >> 2, jj = tid & 3;
      float gf = g_s[b][jj], gi = g_s[b][4 + jj], go = g_s[b][8 + jj], gc = g_s[b][12 + jj];
      float f = 1.f / (1.f + __expf(-gf));
      float i = 1.f / (1.f + __expf(-gi));
      float o = 1.f / (1.f + __expf(-go));
      float cc = tanhf(gc);
      c_state = f * c_state + i * cc;
      float h = o * tanhf(c_state);
      int jg = blk * NJ + jj;
      p.hcur[(size_t)(rbuf ^ 1) * (BB * HH) + b * HH + jg] = (_Float16)h;
      if (l == 0) p.h1seq[((size_t)t * BB + b) * HH + jg] = (_Float16)h;
      else        p.dout[((size_t)b * LL + t) * HH + jg] = h;
    }

    // ---- phase D: two-level grid barrier ----
    __syncthreads();
    if (tid == 0) {
      unsigned target = (unsigned)(s + 1);
      unsigned a1v = __hip_atomic_fetch_add(cnt1, 1u, __ATOMIC_ACQ_REL, __HIP_MEMORY_SCOPE_AGENT);
      if (a1v == 31u) {
        __hip_atomic_store(cnt1, 0u, __ATOMIC_RELAXED, __HIP_MEMORY_SCOPE_AGENT);
        unsigned am = __hip_atomic_fetch_add(cntm, 1u, __ATOMIC_ACQ_REL, __HIP_MEMORY_SCOPE_AGENT);
        if (am == 7u) {
          __hip_atomic_store(cntm, 0u, __ATOMIC_RELAXED, __HIP_MEMORY_SCOPE_AGENT);
          __hip_atomic_store(gen, target, __ATOMIC_RELEASE, __HIP_MEMORY_SCOPE_AGENT);
        } else {
          while (__hip_atomic_load(gen, __ATOMIC_RELAXED, __HIP_MEMORY_SCOPE_AGENT) < target)
            __builtin_amdgcn_s_sleep(1);
          (void)__hip_atomic_load(gen, __ATOMIC_ACQUIRE, __HIP_MEMORY_SCOPE_AGENT);
        }
      } else {
        while (__hip_atomic_load(gen, __ATOMIC_RELAXED, __HIP_MEMORY_SCOPE_AGENT) < target)
          __builtin_amdgcn_s_sleep(1);
        (void)__hip_atomic_load(gen, __ATOMIC_ACQUIRE, __HIP_MEMORY_SCOPE_AGENT);
      }
    }
    __syncthreads();
  }
}

extern "C" void kernel_launch(void* const* d_in, const int* in_sizes, int n_in,
                              void* d_out, int out_size, void* d_ws, size_t ws_size,
                              hipStream_t stream) {
  const float* x = (const float*)d_in[0];
  ScanParams sp;
  sp.W[0] = (const float*)d_in[1]; sp.U[0] = (const float*)d_in[2];   // f
  sp.W[1] = (const float*)d_in[3]; sp.U[1] = (const float*)d_in[4];   // i
  sp.W[2] = (const float*)d_in[5]; sp.U[2] = (const float*)d_in[6];   // o
  sp.W[3] = (const float*)d_in[7]; sp.U[3] = (const float*)d_in[8];   // c
  sp.bias4[0] = (const float*)d_in[9];  sp.bias4[1] = (const float*)d_in[10];
  sp.bias4[2] = (const float*)d_in[11]; sp.bias4[3] = (const float*)d_in[12];

  char* ws = (char*)d_ws;
  sp.xT    = (const _Float16*)(ws + WS_XT16);
  sp.h1seq = (_Float16*)(ws + WS_H1SEQ);
  sp.hcur  = (_Float16*)(ws + WS_HCUR);
  sp.flags = (unsigned*)(ws + WS_FLAGS);
  sp.dout  = (float*)d_out;

  prep_convert<<<16384, 256, 0, stream>>>(x, (_Float16*)(ws + WS_XT16));
  prep_init<<<128, 256, 0, stream>>>((_Float16*)(ws + WS_HCUR), (unsigned*)(ws + WS_FLAGS));
  lstm_scan<<<NBLK, NTHR, 0, stream>>>(sp);
}

// Round 2
// 30943.066 us; speedup vs baseline: 1.4851x; 1.4851x over previous
//
#include <hip/hip_runtime.h>

// ---------------------------------------------------------------------------
// 2-layer LSTM (B=16, L=2048, H=1024), one persistent scan kernel.
// Round-2 change: RMW-tree grid barrier (≈10us/step, serialized ACQ_REL
// atomics) replaced by flag-array store/poll barrier with hand-rolled
// visibility: h published via agent-scope relaxed atomic stores (sc1,
// write-through), producer orders flag with s_waitcnt vmcnt(0), consumers
// poll flags then read hcur with agent-scope relaxed atomic loads.
// x-waves (0-3) never wait on the barrier -> overlap with spin.
// ---------------------------------------------------------------------------

typedef _Float16 half8 __attribute__((ext_vector_type(8)));
typedef float    float4v __attribute__((ext_vector_type(4)));
typedef unsigned long long u64;

#define NBLK 256
#define NTHR 512
#define BB   16
#define LL   2048
#define HH   1024
#define KK   2048      // concat K (x-part 1024 + h-part 1024)
#define NJ   4         // h columns per block
#define NR   16        // gate rows per block (4 gates * NJ)
#define NSTEP 4096     // 2 layers * L

// ws layout (bytes)
#define WS_XT16   0u              // [L][B][H] fp16 : 64 MiB
#define WS_H1SEQ  67108864u       // [L][B][H] fp16 : 64 MiB
#define WS_HCUR   134217728u      // [2][B][H] fp16 : 64 KiB
#define WS_FLAGS  134283264u      // barrier flags (256 u32 used)

struct ScanParams {
  const float* W[4];     // Wf,Wi,Wo,Wc  [2][H][H]
  const float* U[4];     // Uf,Ui,Uo,Uc  [2][H][H]
  const float* bias4[4]; // bf,bi,bo,bc  [2][H]
  const _Float16* xT;    // [L][B][H]
  _Float16* h1seq;       // [L][B][H]
  _Float16* hcur;        // [2][B][H]
  float* dout;           // [B][L][H]
  unsigned* flags;
};

// x [B][L][H] fp32 -> xT [L][B][H] fp16
__global__ void prep_convert(const float* __restrict__ x, _Float16* __restrict__ xT) {
  size_t id = (size_t)blockIdx.x * blockDim.x + threadIdx.x;   // 4,194,304 total
  int k8 = (int)(id & (HH / 8 - 1)) * 8;
  size_t bt = id >> 7;                 // b*L + t
  int b = (int)(bt >> 11);
  int t = (int)(bt & (LL - 1));
  const float* src = x + (bt << 10) + k8;
  float4v v0 = *(const float4v*)(src);
  float4v v1 = *(const float4v*)(src + 4);
  half8 o;
  o[0] = (_Float16)v0[0]; o[1] = (_Float16)v0[1]; o[2] = (_Float16)v0[2]; o[3] = (_Float16)v0[3];
  o[4] = (_Float16)v1[0]; o[5] = (_Float16)v1[1]; o[6] = (_Float16)v1[2]; o[7] = (_Float16)v1[3];
  *(half8*)(xT + (((size_t)t * BB + b) << 10) + k8) = o;
}

__global__ void prep_init(_Float16* hcur, unsigned* flags) {
  int i = blockIdx.x * blockDim.x + threadIdx.x;
  if (i < 2 * BB * HH) hcur[i] = (_Float16)0.f;
  if (i < 1024) flags[i] = 0u;
}

__device__ __forceinline__ float sigm(float x) { return 1.f / (1.f + __expf(-x)); }
__device__ __forceinline__ float tanh_fast(float x) { return 1.f - 2.f / (1.f + __expf(2.f * x)); }

__global__ __launch_bounds__(NTHR, 2) void lstm_scan(ScanParams p) {
  __shared__ _Float16 wlds[2][NR][KK];   // 131072 B, persistent weights
  __shared__ float acc_s[8][16][17];     // per-wave partial D tiles (padded)
  __shared__ float g_s[16][17];          // reduced gates
  __shared__ float bias_s[2][NR];

  const int tid  = threadIdx.x;
  const int blk  = blockIdx.x;
  const int wv   = tid >> 6;
  const int lane = tid & 63;
  const int frow = lane & 15;   // A: batch row ; B: gate row ; same lane mapping
  const int kgrp = lane >> 4;

  // ---- one-time: weights fp32 -> fp16 into LDS, XOR-swizzled rows ----
  for (int idx = tid; idx < 2 * NR * KK; idx += NTHR) {
    int l = idx >> 15;
    int r = (idx >> 11) & (NR - 1);      // r = q*4 + jj
    int k = idx & (KK - 1);
    int q = r >> 2, jj = r & 3;
    int j = blk * NJ + jj;
    float v;
    if (k < HH) v = p.W[q][((size_t)l * HH + j) * HH + k];
    else        v = p.U[q][((size_t)l * HH + j) * HH + (k - HH)];
    unsigned bo = ((unsigned)(k * 2)) ^ ((unsigned)((r & 7) << 4));
    *(_Float16*)((char*)&wlds[l][r][0] + bo) = (_Float16)v;
  }
  if (tid < 2 * NR) {
    int l = tid >> 4, r = tid & 15;
    int q = r >> 2, jj = r & 3;
    bias_s[l][r] = p.bias4[q][l * HH + blk * NJ + jj];
  }
  // cell state: lanes 0..15 of wave 0; lane b holds c for batch b, cols jj=0..3
  float cst0 = 0.f, cst1 = 0.f, cst2 = 0.f, cst3 = 0.f;
  __syncthreads();

  unsigned* flags = p.flags;

  for (int s = 0; s < NSTEP; ++s) {
    const int l    = s >> 11;
    const int t    = s & (LL - 1);
    const int rbuf = s & 1;

    // ---- phase A: per-wave K-slice MFMA ----
    half8 aop[8], bop[8];
    if (wv < 4) {
      // x-part: no dependency on the grid barrier -> overlaps h-wave spin
      const _Float16* inp = (l == 0) ? p.xT : p.h1seq;
      const _Float16* abase = inp + (size_t)t * (BB * HH) + frow * HH + (wv & 3) * 256 + kgrp * 8;
#pragma unroll
      for (int kk = 0; kk < 8; ++kk)
        aop[kk] = *(const half8*)(abase + kk * 32);
    } else {
      // wait until every block finished step s-1 (flags >= s)
      const unsigned target = (unsigned)s;
      const int fidx = tid - 256;
      while (__hip_atomic_load(&flags[fidx], __ATOMIC_RELAXED, __HIP_MEMORY_SCOPE_AGENT) < target)
        __builtin_amdgcn_s_sleep(1);
      // fresh h from the coherence point (bypass possibly-stale L1/L2)
      const u64* hb = (const u64*)(p.hcur + (size_t)rbuf * (BB * HH) + frow * HH + (wv & 3) * 256 + kgrp * 8);
#pragma unroll
      for (int kk = 0; kk < 8; ++kk) {
        union { u64 q[2]; half8 v; } u;
        u.q[0] = __hip_atomic_load(hb + kk * 8 + 0, __ATOMIC_RELAXED, __HIP_MEMORY_SCOPE_AGENT);
        u.q[1] = __hip_atomic_load(hb + kk * 8 + 1, __ATOMIC_RELAXED, __HIP_MEMORY_SCOPE_AGENT);
        aop[kk] = u.v;
      }
    }
    const int kw0 = wv * 256 + kgrp * 8;
    const char* wrow = (const char*)&wlds[l][frow][0];
#pragma unroll
    for (int kk = 0; kk < 8; ++kk) {
      unsigned bo = (unsigned)((kw0 + kk * 32) * 2) ^ ((unsigned)((frow & 7) << 4));
      bop[kk] = *(const half8*)(wrow + bo);
    }
    float4v a0 = {0.f, 0.f, 0.f, 0.f}, a1 = {0.f, 0.f, 0.f, 0.f};
#pragma unroll
    for (int kk = 0; kk < 8; kk += 2) {
      a0 = __builtin_amdgcn_mfma_f32_16x16x32_f16(aop[kk],     bop[kk],     a0, 0, 0, 0);
      a1 = __builtin_amdgcn_mfma_f32_16x16x32_f16(aop[kk + 1], bop[kk + 1], a1, 0, 0, 0);
    }
    a0 += a1;
#pragma unroll
    for (int v = 0; v < 4; ++v)
      acc_s[wv][kgrp * 4 + v][frow] = a0[v];   // D: row=batch=(lane>>4)*4+v, col=gaterow=lane&15
    __syncthreads();

    // ---- phase B: reduce 8 partials + bias ----
    if (tid < 256) {
      int b = tid >> 4, r = tid & 15;
      float g = bias_s[l][r];
#pragma unroll
      for (int w = 0; w < 8; ++w) g += acc_s[w][b][r];
      g_s[b][r] = g;
    }
    __syncthreads();

    // ---- phase C: LSTM cell (16 lanes, one batch row each, 4 cols) ----
    if (tid < 16) {
      const int b = tid;
      union { u64 q; _Float16 hv[4]; } up;
      float h0f, h1f, h2f, h3f;
      {
        float f = sigm(g_s[b][0]), i = sigm(g_s[b][4]), o = sigm(g_s[b][8]);
        cst0 = f * cst0 + i * tanh_fast(g_s[b][12]);
        h0f = o * tanh_fast(cst0); up.hv[0] = (_Float16)h0f;
      }
      {
        float f = sigm(g_s[b][1]), i = sigm(g_s[b][5]), o = sigm(g_s[b][9]);
        cst1 = f * cst1 + i * tanh_fast(g_s[b][13]);
        h1f = o * tanh_fast(cst1); up.hv[1] = (_Float16)h1f;
      }
      {
        float f = sigm(g_s[b][2]), i = sigm(g_s[b][6]), o = sigm(g_s[b][10]);
        cst2 = f * cst2 + i * tanh_fast(g_s[b][14]);
        h2f = o * tanh_fast(cst2); up.hv[2] = (_Float16)h2f;
      }
      {
        float f = sigm(g_s[b][3]), i = sigm(g_s[b][7]), o = sigm(g_s[b][11]);
        cst3 = f * cst3 + i * tanh_fast(g_s[b][15]);
        h3f = o * tanh_fast(cst3); up.hv[3] = (_Float16)h3f;
      }
      const int jg0 = blk * NJ;
      u64* hd = (u64*)(p.hcur + (size_t)(rbuf ^ 1) * (BB * HH) + b * HH + jg0);
      __hip_atomic_store(hd, up.q, __ATOMIC_RELAXED, __HIP_MEMORY_SCOPE_AGENT);
      if (l == 0) {
        u64* sd = (u64*)(p.h1seq + ((size_t)t * BB + b) * HH + jg0);
        __hip_atomic_store(sd, up.q, __ATOMIC_RELAXED, __HIP_MEMORY_SCOPE_AGENT);
      } else {
        float4v ov; ov[0] = h0f; ov[1] = h1f; ov[2] = h2f; ov[3] = h3f;
        *(float4v*)(p.dout + ((size_t)b * LL + t) * HH + jg0) = ov;
      }
    }
    // ---- arrival: order h stores (sc1, write-through) before flag store ----
    if (wv == 0) {
      asm volatile("s_waitcnt vmcnt(0)" ::: "memory");
      if (lane == 0)
        __hip_atomic_store(&flags[blk], (unsigned)(s + 1), __ATOMIC_RELAXED, __HIP_MEMORY_SCOPE_AGENT);
    }
    // no trailing __syncthreads: x-waves of step s+1 only touch their own
    // acc_s slots (dead after phase B) and h-waves re-wait on flags.
  }
}

extern "C" void kernel_launch(void* const* d_in, const int* in_sizes, int n_in,
                              void* d_out, int out_size, void* d_ws, size_t ws_size,
                              hipStream_t stream) {
  const float* x = (const float*)d_in[0];
  ScanParams sp;
  sp.W[0] = (const float*)d_in[1]; sp.U[0] = (const float*)d_in[2];   // f
  sp.W[1] = (const float*)d_in[3]; sp.U[1] = (const float*)d_in[4];   // i
  sp.W[2] = (const float*)d_in[5]; sp.U[2] = (const float*)d_in[6];   // o
  sp.W[3] = (const float*)d_in[7]; sp.U[3] = (const float*)d_in[8];   // c
  sp.bias4[0] = (const float*)d_in[9];  sp.bias4[1] = (const float*)d_in[10];
  sp.bias4[2] = (const float*)d_in[11]; sp.bias4[3] = (const float*)d_in[12];

  char* ws = (char*)d_ws;
  sp.xT    = (const _Float16*)(ws + WS_XT16);
  sp.h1seq = (_Float16*)(ws + WS_H1SEQ);
  sp.hcur  = (_Float16*)(ws + WS_HCUR);
  sp.flags = (unsigned*)(ws + WS_FLAGS);
  sp.dout  = (float*)d_out;

  prep_convert<<<16384, 256, 0, stream>>>(x, (_Float16*)(ws + WS_XT16));
  prep_init<<<128, 256, 0, stream>>>((_Float16*)(ws + WS_HCUR), (unsigned*)(ws + WS_FLAGS));
  lstm_scan<<<NBLK, NTHR, 0, stream>>>(sp);
}